// Round 7
// baseline (252.003 us; speedup 1.0000x reference)
//
#include <hip/hip_runtime.h>
#include <hip/hip_bf16.h>

#define B_SZ   128
#define T_SZ   2048
#define ENCH   512
#define ATTN_  128
#define S_SPLIT 8
#define CHUNK  256               // rows per chunk
#define TPC    16                // 16-row tiles per chunk
#define CPB    2                 // chunks per block
#define TILES  (CPB * TPC)       // 32 tiles per block
#define NBLK   (B_SZ * S_SPLIT / CPB)   // 512 blocks

typedef __attribute__((ext_vector_type(8))) short short8;
typedef __attribute__((ext_vector_type(4))) float f32x4;

__device__ __forceinline__ unsigned short f2bf_rne(float f) {
  unsigned u = __builtin_bit_cast(unsigned, f);
  u += 0x7FFFu + ((u >> 16) & 1u);
  return (unsigned short)(u >> 16);
}
__device__ __forceinline__ float fast_tanh(float x) {
  float e = __expf(2.f * x);
  return 1.f - __fdividef(2.f, e + 1.f);
}
__device__ __forceinline__ short8 pack8(float4 a, float4 b) {
  union { unsigned u[4]; short8 s; } r;
  asm("v_cvt_pk_bf16_f32 %0, %1, %2" : "=v"(r.u[0]) : "v"(a.x), "v"(a.y));
  asm("v_cvt_pk_bf16_f32 %0, %1, %2" : "=v"(r.u[1]) : "v"(a.z), "v"(a.w));
  asm("v_cvt_pk_bf16_f32 %0, %1, %2" : "=v"(r.u[2]) : "v"(b.x), "v"(b.y));
  asm("v_cvt_pk_bf16_f32 %0, %1, %2" : "=v"(r.u[3]) : "v"(b.z), "v"(b.w));
  return r.s;
}
template<int CTRL>
__device__ __forceinline__ float dpp_add(float v) {
  int t = __builtin_amdgcn_update_dpp(0, __builtin_bit_cast(int, v),
                                      CTRL, 0xf, 0xf, true);
  return v + __builtin_bit_cast(float, t);
}
__device__ __forceinline__ float sum16(float v) {
  v = dpp_add<0xB1>(v);    // quad_perm xor1
  v = dpp_add<0x4E>(v);    // quad_perm xor2
  v = dpp_add<0x141>(v);   // row_half_mirror
  v = dpp_add<0x140>(v);   // row_mirror
  return v;
}
__device__ __forceinline__ void gload_lds16(const float* g, float* l) {
  __builtin_amdgcn_global_load_lds(
      (const __attribute__((address_space(1))) void*)g,
      (__attribute__((address_space(3))) void*)l, 16, 0, 0);
}

// ---- K0b: W_enc fp32 -> bf16 FRAGMENT-LINEAR ----
// o[((cg*16+ks)*64 + l)*8 + j] = bf16(W[cg*16 + (l&15)][ks*32 + (l>>4)*8 + j])
__global__ void k_convert_wfrag(const float* __restrict__ w,
                                unsigned short* __restrict__ o) {
  int idx = blockIdx.x * 256 + threadIdx.x;   // 8192 threads
  int l   = idx & 63;
  int wks = idx >> 6;
  int cg  = wks >> 4, ks = wks & 15;
  int row = cg * 16 + (l & 15);
  int col = ks * 32 + (l >> 4) * 8;
  const float4* src = reinterpret_cast<const float4*>(w + row * ENCH + col);
  float4 v0 = src[0], v1 = src[1];
  short8 r;
  r[0] = (short)f2bf_rne(v0.x); r[1] = (short)f2bf_rne(v0.y);
  r[2] = (short)f2bf_rne(v0.z); r[3] = (short)f2bf_rne(v0.w);
  r[4] = (short)f2bf_rne(v1.x); r[5] = (short)f2bf_rne(v1.y);
  r[6] = (short)f2bf_rne(v1.z); r[7] = (short)f2bf_rne(v1.w);
  *reinterpret_cast<short8*>(o + (size_t)idx * 8) = r;
}

// ---- K0a: dec_proj ----
__global__ void k_decproj(const float* __restrict__ dec,
                          const float* __restrict__ wdec,
                          float* __restrict__ out) {
  __shared__ float dh[ENCH];
  int b = blockIdx.x, tid = threadIdx.x;    // 128 threads
  for (int i = tid; i < ENCH; i += 128) dh[i] = dec[b * ENCH + i];
  __syncthreads();
  const float4* wr4 = reinterpret_cast<const float4*>(wdec + tid * ENCH);
  float acc = 0.f;
  for (int h4 = 0; h4 < ENCH / 4; ++h4) {
    float4 w4 = wr4[h4];
    acc += dh[h4 * 4 + 0] * w4.x + dh[h4 * 4 + 1] * w4.y +
           dh[h4 * 4 + 2] * w4.z + dh[h4 * 4 + 3] * w4.w;
  }
  out[b * ATTN_ + tid] = acc;
}

// ---- K1: col-partitioned, global_load_lds ring-2. ----
// Pipeline: stage(t+1) issued right after B1(t); drained by B1(t+1)'s
// __syncthreads vmcnt(0) -> full overlap with iter t's compute, no counted
// vmcnt needed. Raw s_barrier (B3) only between score atomics and softmax so
// in-flight stage(t+1) loads are NOT drained mid-iteration.
// Swizzle (rule #21 both-sides): LDS 16B-chunk c of row r holds global chunk
// c^(r&7); staged by pre-swizzling the per-lane GLOBAL address (LDS dest
// linear), read back with the same XOR.
__global__ __launch_bounds__(512, 4) void k_main(
    const float* __restrict__ enc,            // [B,T,512] fp32
    const unsigned short* __restrict__ wfrag, // frag-linear bf16 W_enc
    const float* __restrict__ decproj,        // [B,128] fp32
    const float* __restrict__ vw,             // [128] fp32
    float* __restrict__ scores_raw,           // [B,T] raw scores
    float* __restrict__ ctx_part,             // [B*8][512]
    float* __restrict__ ml_part)              // [B*8][2]
{
  const int tid  = threadIdx.x;
  const int lane = tid & 63;
  const int wave = tid >> 6;      // 8 waves; wave owns cols [wave*16, +16)
  const int l15  = lane & 15;
  const int g    = lane >> 4;

  __shared__ float ring[2][TPC * ENCH];       // 2 x 32 KiB fp32 tiles (16 rows)
  __shared__ float sc[2][16];                 // score slots

  // persistent B fragments (16 KB per wave, from L2)
  short8 bfrag[16];
  {
    const unsigned short* wp = wfrag + ((size_t)(wave * 16) * 64 + lane) * 8;
#pragma unroll
    for (int ks = 0; ks < 16; ++ks)
      bfrag[ks] = *reinterpret_cast<const short8*>(wp + ks * 512);
  }
  const float vlane = vw[wave * 16 + l15];
  float dl[CPB];
#pragma unroll
  for (int c = 0; c < CPB; ++c) {
    int cid = blockIdx.x * CPB + c;
    dl[c] = decproj[(cid >> 3) * ATTN_ + wave * 16 + l15];
  }
  if (tid < 32) ((float*)sc)[tid] = 0.f;

  auto stage = [&](int tt) {
    int cid = blockIdx.x * CPB + (tt >> 4);
    size_t rbase = (size_t)(cid >> 3) * T_SZ + (cid & 7) * CHUNK + (tt & 15) * 16;
    float* dst = &ring[tt & 1][0];
#pragma unroll
    for (int q = 0; q < 4; ++q) {
      int i = wave * 4 + q;            // 32 insts cover 16 rows x 2 halves
      int r = i >> 1, h = i & 1;
      const float* gsrc = enc + (rbase + r) * ENCH + h * 256 + ((lane ^ (r & 7)) << 2);
      gload_lds16(gsrc, dst + i * 256);   // LDS dest linear: base + lane*16B
    }
  };

  stage(0);   // prologue: tile 0 in flight

  float m_run = -INFINITY, l_run = 0.f, ctx = 0.f;   // thread owns h = tid

#pragma unroll 1
  for (int t = 0; t < TILES; ++t) {
    const int slot = t & 1;
    const int c    = t >> 4;
    const int cid  = blockIdx.x * CPB + c;
    const int b    = cid >> 3, sp = cid & 7;

    // B1: drains vmcnt(0)+lgkmcnt(0) -> tile t complete & visible; prev
    // iter's LDS reads serviced (safe to overwrite below).
    __syncthreads();
    if (tid < 16) sc[slot ^ 1][tid] = 0.f; // zero slot for tile t+1
    if (t + 1 < TILES) stage(t + 1);       // in flight until B1 of iter t+1

    // ---- MFMA: proj[16 rows][wave's 16 cols] ----
    const float* tile = &ring[slot][0];
    const int sw = l15 & 7;
    f32x4 acc = (f32x4){0.f, 0.f, 0.f, 0.f};
#pragma unroll
    for (int ks = 0; ks < 16; ++ks) {
      int c0 = (ks * 8 + g * 2) ^ sw;     // 16B-chunk index, swizzle-read
      float4 a0 = *reinterpret_cast<const float4*>(tile + l15 * 512 + c0 * 4);
      float4 a1 = *reinterpret_cast<const float4*>(tile + l15 * 512 + (c0 ^ 1) * 4);
      acc = __builtin_amdgcn_mfma_f32_16x16x32_bf16(pack8(a0, a1), bfrag[ks], acc, 0, 0, 0);
    }

    // ---- scores: row = 4g+r, sum over wave's 16 cols (DPP), LDS atomic ----
    const float dlane = dl[c];
    float er0 = sum16(fast_tanh(acc[0] + dlane) * vlane);
    float er1 = sum16(fast_tanh(acc[1] + dlane) * vlane);
    float er2 = sum16(fast_tanh(acc[2] + dlane) * vlane);
    float er3 = sum16(fast_tanh(acc[3] + dlane) * vlane);
    if (l15 == 0) {
      atomicAdd(&sc[slot][g * 4 + 0], er0);
      atomicAdd(&sc[slot][g * 4 + 1], er1);
      atomicAdd(&sc[slot][g * 4 + 2], er2);
      atomicAdd(&sc[slot][g * 4 + 3], er3);
    }
    // B3: per-wave atomics retired, then raw barrier (keeps stage(t+1)
    // loads in flight; __syncthreads here would drain them).
    asm volatile("s_waitcnt lgkmcnt(0)" ::: "memory");
    __builtin_amdgcn_s_barrier();
    asm volatile("" ::: "memory");

    const int trow = sp * CHUNK + (t & 15) * 16;
    if (tid < 16)
      scores_raw[(size_t)b * T_SZ + trow + tid] = sc[slot][tid];

    // ---- online softmax + ctx (thread owns h = tid, fp32 from LDS) ----
    float s16v[16];
#pragma unroll
    for (int k = 0; k < 16; ++k) s16v[k] = sc[slot][k];
    float smax = s16v[0];
#pragma unroll
    for (int k = 1; k < 16; ++k) smax = fmaxf(smax, s16v[k]);
    float m_new = fmaxf(m_run, smax);
    float scale = __expf(m_run - m_new);   // exp(-inf)=0 first tile
    l_run *= scale; ctx *= scale;
    const int hc = tid >> 2, hr = tid & 3;
#pragma unroll
    for (int k = 0; k < 16; ++k) {
      float p = __expf(s16v[k] - m_new);
      l_run += p;
      ctx += p * tile[k * 512 + ((hc ^ (k & 7)) << 2) + hr];
    }
    m_run = m_new;

    if ((t & 15) == 15) {                  // chunk boundary: flush partials
      ctx_part[(size_t)cid * ENCH + tid] = ctx;
      if (tid == 0) { ml_part[cid * 2] = m_run; ml_part[cid * 2 + 1] = l_run; }
      ctx = 0.f; l_run = 0.f; m_run = -INFINITY;
    }
  }
}

// ---- K2: merge 8 splits per batch; normalize weights in place ----
__global__ void k_combine(const float* __restrict__ ctx_part,
                          const float* __restrict__ ml_part,
                          float* __restrict__ out_ctx,   // [B,512]
                          float* __restrict__ weights)   // [B,T], raw scores
{
  __shared__ float fac[S_SPLIT];
  __shared__ float Msh, Lsh;
  int b = blockIdx.x, tid = threadIdx.x;   // 256 threads
  if (tid == 0) {
    float M = -INFINITY;
    for (int s2 = 0; s2 < S_SPLIT; ++s2)
      M = fmaxf(M, ml_part[(b * S_SPLIT + s2) * 2]);
    float L = 0.f;
    for (int s2 = 0; s2 < S_SPLIT; ++s2) {
      float f = __expf(ml_part[(b * S_SPLIT + s2) * 2] - M);
      fac[s2] = f;
      L += f * ml_part[(b * S_SPLIT + s2) * 2 + 1];
    }
    Msh = M; Lsh = L;
  }
  __syncthreads();
  float M = Msh, Linv = 1.f / Lsh;
  for (int h = tid; h < ENCH; h += 256) {
    float a = 0.f;
    for (int s2 = 0; s2 < S_SPLIT; ++s2)
      a += ctx_part[(b * S_SPLIT + s2) * ENCH + h] * fac[s2];
    out_ctx[b * ENCH + h] = a * Linv;
  }
  for (int t = tid; t < T_SZ; t += 256) {
    float raw = weights[(size_t)b * T_SZ + t];
    weights[(size_t)b * T_SZ + t] = __expf(raw - M) * Linv;
  }
}

extern "C" void kernel_launch(void* const* d_in, const int* in_sizes, int n_in,
                              void* d_out, int out_size, void* d_ws, size_t ws_size,
                              hipStream_t stream) {
  const float* enc  = (const float*)d_in[0];
  const float* dec  = (const float*)d_in[1];
  const float* wenc = (const float*)d_in[2];
  const float* wdec = (const float*)d_in[3];
  const float* vw   = (const float*)d_in[4];

  float* out     = (float*)d_out;
  float* out_ctx = out;                       // [B,512]
  float* out_w   = out + B_SZ * ENCH;         // [B,T] raw scores -> weights

  char* ws = (char*)d_ws;
  unsigned short* wfrag = (unsigned short*)ws;                      // 131072 B
  float* decproj  = (float*)(ws + 131072);                          // 65536 B
  float* ml_part  = (float*)(ws + 131072 + 65536);                  // 8192 B
  float* ctx_part = (float*)(ws + 131072 + 65536 + 8192);           // 2 MiB

  hipLaunchKernelGGL(k_convert_wfrag, dim3(32), dim3(256), 0, stream, wenc, wfrag);
  hipLaunchKernelGGL(k_decproj, dim3(B_SZ), dim3(128), 0, stream, dec, wdec, decproj);
  hipLaunchKernelGGL(k_main, dim3(NBLK), dim3(512), 0, stream,
                     enc, wfrag, decproj, vw, out_w, ctx_part, ml_part);
  hipLaunchKernelGGL(k_combine, dim3(B_SZ), dim3(256), 0, stream,
                     ctx_part, ml_part, out_ctx, out_w);
}

// Round 8
// 179.415 us; speedup vs baseline: 1.4046x; 1.4046x over previous
//
#include <hip/hip_runtime.h>
#include <hip/hip_bf16.h>

#define B_SZ   128
#define T_SZ   2048
#define ENCH   512
#define ATTN_  128
#define NBLK   256               // persistent, 1 block/CU
#define STRIPS_PER_BLK 8         // 2048 strips-of-128-rows / 256 blocks

typedef __attribute__((ext_vector_type(8))) short short8;
typedef __attribute__((ext_vector_type(4))) float f32x4;

__device__ __forceinline__ unsigned short f2bf_rne(float f) {
  unsigned u = __builtin_bit_cast(unsigned, f);
  u += 0x7FFFu + ((u >> 16) & 1u);
  return (unsigned short)(u >> 16);
}
__device__ __forceinline__ float fast_tanh(float x) {
  float e = __expf(2.f * x);
  return 1.f - __fdividef(2.f, e + 1.f);
}
__device__ __forceinline__ short8 pack8(float4 a, float4 b) {
  union { unsigned u[4]; short8 s; } r;
  asm("v_cvt_pk_bf16_f32 %0, %1, %2" : "=v"(r.u[0]) : "v"(a.x), "v"(a.y));
  asm("v_cvt_pk_bf16_f32 %0, %1, %2" : "=v"(r.u[1]) : "v"(a.z), "v"(a.w));
  asm("v_cvt_pk_bf16_f32 %0, %1, %2" : "=v"(r.u[2]) : "v"(b.x), "v"(b.y));
  asm("v_cvt_pk_bf16_f32 %0, %1, %2" : "=v"(r.u[3]) : "v"(b.z), "v"(b.w));
  return r.s;
}
template<int CTRL>
__device__ __forceinline__ float dpp_add(float v) {
  int t = __builtin_amdgcn_update_dpp(0, __builtin_bit_cast(int, v),
                                      CTRL, 0xf, 0xf, true);
  return v + __builtin_bit_cast(float, t);
}
__device__ __forceinline__ float sum16(float v) {
  v = dpp_add<0xB1>(v);    // quad_perm xor1
  v = dpp_add<0x4E>(v);    // quad_perm xor2
  v = dpp_add<0x141>(v);   // row_half_mirror
  v = dpp_add<0x140>(v);   // row_mirror
  return v;
}

// ---- K0b: W_enc fp32 -> bf16 FRAGMENT-LINEAR ----
// o[((cg*16+ks)*64 + l)*8 + j] = bf16(W[cg*16 + (l&15)][ks*32 + (l>>4)*8 + j])
__global__ void k_convert_wfrag(const float* __restrict__ w,
                                unsigned short* __restrict__ o) {
  int idx = blockIdx.x * 256 + threadIdx.x;   // 8192 threads
  int l   = idx & 63;
  int wks = idx >> 6;
  int cg  = wks >> 4, ks = wks & 15;
  int row = cg * 16 + (l & 15);
  int col = ks * 32 + (l >> 4) * 8;
  const float4* src = reinterpret_cast<const float4*>(w + row * ENCH + col);
  float4 v0 = src[0], v1 = src[1];
  short8 r;
  r[0] = (short)f2bf_rne(v0.x); r[1] = (short)f2bf_rne(v0.y);
  r[2] = (short)f2bf_rne(v0.z); r[3] = (short)f2bf_rne(v0.w);
  r[4] = (short)f2bf_rne(v1.x); r[5] = (short)f2bf_rne(v1.y);
  r[6] = (short)f2bf_rne(v1.z); r[7] = (short)f2bf_rne(v1.w);
  *reinterpret_cast<short8*>(o + (size_t)idx * 8) = r;
}

// ---- K0a: dec_proj ----
__global__ void k_decproj(const float* __restrict__ dec,
                          const float* __restrict__ wdec,
                          float* __restrict__ out) {
  __shared__ float dh[ENCH];
  int b = blockIdx.x, tid = threadIdx.x;    // 128 threads
  for (int i = tid; i < ENCH; i += 128) dh[i] = dec[b * ENCH + i];
  __syncthreads();
  const float4* wr4 = reinterpret_cast<const float4*>(wdec + tid * ENCH);
  float acc = 0.f;
  for (int h4 = 0; h4 < ENCH / 4; ++h4) {
    float4 w4 = wr4[h4];
    acc += dh[h4 * 4 + 0] * w4.x + dh[h4 * 4 + 1] * w4.y +
           dh[h4 * 4 + 2] * w4.z + dh[h4 * 4 + 3] * w4.w;
  }
  out[b * ATTN_ + tid] = acc;
}

// ---- K1: read-once, barrier-free, register-resident strips. ----
// 512 thr (8 waves, 2/SIMD -> 256 VGPR budget). W_enc in 128 KiB LDS (staged
// once). Each wave owns a 16-row strip end-to-end: the full 16x512 fp32 strip
// lives in 128 VGPRs (32 outstanding dwordx4 loads = max MLP), MFMA -> scores
// -> wave-private softmax -> ctx via DPP reduce from the SAME registers.
// Partials to global; k_combine merges 128 per batch.
__global__ __launch_bounds__(512, 2) void k_main(
    const float* __restrict__ enc,            // [B,T,512] fp32
    const unsigned short* __restrict__ wfrag, // frag-linear bf16 W_enc
    const float* __restrict__ decproj,        // [B,128] fp32
    const float* __restrict__ vw,             // [128] fp32
    float* __restrict__ scores_raw,           // [B,T] raw scores
    float* __restrict__ ctx_part,             // [B*128][512]
    float* __restrict__ ml_part)              // [B*128][2]
{
  const int tid  = threadIdx.x;
  const int lane = tid & 63;
  const int wid  = tid >> 6;       // 8 waves
  const int l15  = lane & 15;
  const int g    = lane >> 4;

  __shared__ unsigned short w_lds[ATTN_ * ENCH];  // 128 KiB frag-linear

#pragma unroll
  for (int r = 0; r < 16; ++r) {
    int i = r * 512 + tid;
    reinterpret_cast<short8*>(w_lds)[i] = reinterpret_cast<const short8*>(wfrag)[i];
  }
  float vv[8];
#pragma unroll
  for (int cg = 0; cg < 8; ++cg) vv[cg] = vw[cg * 16 + l15];
  __syncthreads();   // the only block barrier

#pragma unroll 1
  for (int i = 0; i < STRIPS_PER_BLK; ++i) {
    const int cid = blockIdx.x * STRIPS_PER_BLK + i;  // 0..2047
    const int b   = cid >> 4;
    const int s16 = cid & 15;            // 128-row window within batch
    const int row0 = s16 * 128 + wid * 16;
    const float* arow = enc + ((size_t)b * T_SZ + row0 + l15) * ENCH + g * 8;

    // ---- the ONLY enc read: whole strip into registers, 32 loads in flight --
    float4 r0[16], r1[16];
#pragma unroll
    for (int ks = 0; ks < 16; ++ks) {
      r0[ks] = *reinterpret_cast<const float4*>(arow + ks * 32);
      r1[ks] = *reinterpret_cast<const float4*>(arow + ks * 32 + 4);
    }

    float dv[8];
#pragma unroll
    for (int cg = 0; cg < 8; ++cg) dv[cg] = decproj[b * ATTN_ + cg * 16 + l15];

    // ---- MFMA: proj[16 rows][128 cols] ----
    f32x4 acc[8];
#pragma unroll
    for (int cg = 0; cg < 8; ++cg) acc[cg] = (f32x4){0.f, 0.f, 0.f, 0.f};
#pragma unroll
    for (int ks = 0; ks < 16; ++ks) {
      short8 af = pack8(r0[ks], r1[ks]);
      const char* wb = (const char*)w_lds + ks * 1024 + lane * 16;
#pragma unroll
      for (int cg = 0; cg < 8; ++cg) {
        short8 bf = *reinterpret_cast<const short8*>(wb + cg * 16384);
        acc[cg] = __builtin_amdgcn_mfma_f32_16x16x32_bf16(af, bf, acc[cg], 0, 0, 0);
      }
    }

    // ---- scores: row = 4g+r; sum over 128 cols via DPP ----
    float er[4];
#pragma unroll
    for (int r = 0; r < 4; ++r) {
      float e = 0.f;
#pragma unroll
      for (int cg = 0; cg < 8; ++cg)
        e += fast_tanh(acc[cg][r] + dv[cg]) * vv[cg];
      er[r] = sum16(e);
    }
    if (l15 == 0) {
#pragma unroll
      for (int r = 0; r < 4; ++r)
        scores_raw[(size_t)b * T_SZ + row0 + g * 4 + r] = er[r];
    }

    // ---- wave-private softmax over 16 rows ----
    float mg = fmaxf(fmaxf(er[0], er[1]), fmaxf(er[2], er[3]));
    mg = fmaxf(mg, __shfl_xor(mg, 16));
    mg = fmaxf(mg, __shfl_xor(mg, 32));
    float x0 = __expf(er[0] - mg), x1 = __expf(er[1] - mg);
    float x2 = __expf(er[2] - mg), x3 = __expf(er[3] - mg);
    float xs = (x0 + x1) + (x2 + x3);
    xs += __shfl_xor(xs, 16);
    xs += __shfl_xor(xs, 32);
    const float l_run = xs;
    float sel = (l15 & 3) == 0 ? er[0]
              : (l15 & 3) == 1 ? er[1]
              : (l15 & 3) == 2 ? er[2] : er[3];
    float smine = __shfl(sel, ((l15 >> 2) << 4) | (l15 & 3));
    const float p_me = __expf(smine - mg);   // p for row l15

    // ---- ctx from the SAME fp32 registers; DPP 16-lane reduce ----
    // lane (l15,g) contributes row l15; output lane owns h = l15*32 + g*8 + j
    float ctx8[8];
#pragma unroll
    for (int j = 0; j < 8; ++j) ctx8[j] = 0.f;
#pragma unroll
    for (int ks = 0; ks < 16; ++ks) {
      float c[8];
      c[0] = p_me * r0[ks].x; c[1] = p_me * r0[ks].y;
      c[2] = p_me * r0[ks].z; c[3] = p_me * r0[ks].w;
      c[4] = p_me * r1[ks].x; c[5] = p_me * r1[ks].y;
      c[6] = p_me * r1[ks].z; c[7] = p_me * r1[ks].w;
#pragma unroll
      for (int j = 0; j < 8; ++j) c[j] = sum16(c[j]);
      if (l15 == ks) {
#pragma unroll
        for (int j = 0; j < 8; ++j) ctx8[j] = c[j];
      }
    }

    // ---- per-wave partial out (widx = b*128 + s16*8 + wid) ----
    const size_t widx = (size_t)b * 128 + s16 * 8 + wid;
    float* cp = ctx_part + widx * ENCH + l15 * 32 + g * 8;
    *reinterpret_cast<float4*>(cp)     = (float4){ctx8[0], ctx8[1], ctx8[2], ctx8[3]};
    *reinterpret_cast<float4*>(cp + 4) = (float4){ctx8[4], ctx8[5], ctx8[6], ctx8[7]};
    if (lane == 0) {
      ml_part[widx * 2 + 0] = mg;
      ml_part[widx * 2 + 1] = l_run;
    }
  }
}

// ---- K2: merge 128 per-wave partials per batch; normalize weights ----
__global__ void k_combine(const float* __restrict__ ctx_part,
                          const float* __restrict__ ml_part,
                          float* __restrict__ out_ctx,   // [B,512]
                          float* __restrict__ weights)   // [B,T], raw scores
{
  __shared__ float msh[128], lsh[128], fac[128];
  int b = blockIdx.x, tid = threadIdx.x;   // 256 threads
  if (tid < 128) {
    msh[tid] = ml_part[((size_t)b * 128 + tid) * 2 + 0];
    lsh[tid] = ml_part[((size_t)b * 128 + tid) * 2 + 1];
  }
  __syncthreads();
  float M = msh[0];
  for (int w = 1; w < 128; ++w) M = fmaxf(M, msh[w]);
  if (tid < 128) fac[tid] = __expf(msh[tid] - M);
  __syncthreads();
  float L = 0.f;
  for (int w = 0; w < 128; ++w) L += fac[w] * lsh[w];
  float Linv = 1.f / L;
  for (int h = tid; h < ENCH; h += 256) {
    float a = 0.f;
    for (int w = 0; w < 128; ++w)
      a += fac[w] * ctx_part[((size_t)b * 128 + w) * ENCH + h];
    out_ctx[b * ENCH + h] = a * Linv;
  }
  for (int t = tid; t < T_SZ; t += 256) {
    float raw = weights[(size_t)b * T_SZ + t];
    weights[(size_t)b * T_SZ + t] = __expf(raw - M) * Linv;
  }
}

extern "C" void kernel_launch(void* const* d_in, const int* in_sizes, int n_in,
                              void* d_out, int out_size, void* d_ws, size_t ws_size,
                              hipStream_t stream) {
  const float* enc  = (const float*)d_in[0];
  const float* dec  = (const float*)d_in[1];
  const float* wenc = (const float*)d_in[2];
  const float* wdec = (const float*)d_in[3];
  const float* vw   = (const float*)d_in[4];

  float* out     = (float*)d_out;
  float* out_ctx = out;                       // [B,512]
  float* out_w   = out + B_SZ * ENCH;         // [B,T] raw scores -> weights

  char* ws = (char*)d_ws;
  unsigned short* wfrag = (unsigned short*)ws;                      // 131072 B
  float* decproj  = (float*)(ws + 131072);                          // 65536 B
  float* ml_part  = (float*)(ws + 131072 + 65536);                  // 131072 B
  float* ctx_part = (float*)(ws + 131072 + 65536 + 131072);         // 32 MiB

  hipLaunchKernelGGL(k_convert_wfrag, dim3(32), dim3(256), 0, stream, wenc, wfrag);
  hipLaunchKernelGGL(k_decproj, dim3(B_SZ), dim3(128), 0, stream, dec, wdec, decproj);
  hipLaunchKernelGGL(k_main, dim3(NBLK), dim3(512), 0, stream,
                     enc, wfrag, decproj, vw, out_w, ctx_part, ml_part);
  hipLaunchKernelGGL(k_combine, dim3(B_SZ), dim3(256), 0, stream,
                     ctx_part, ml_part, out_ctx, out_w);
}